// Round 1
// baseline (175.617 us; speedup 1.0000x reference)
//
#include <hip/hip_runtime.h>
#include <hip/hip_bf16.h>

typedef __attribute__((ext_vector_type(8))) short s16x8;
typedef __attribute__((ext_vector_type(4))) float f32x4;
typedef unsigned short u16;

#define NTOK 49
#define CDIM 128
#define NH 4
#define NWIN 4096

// LDS geometry (elements of u16/bf16). All row strides keep 16B alignment for b128 reads.
#define XT_STRIDE 136   // x tile / attn-out tile: [64][136]
#define QK_STRIDE 40    // q,k per head: [64][40]
#define VT_STRIDE 72    // v transposed per head: [32][72]; p aliases q+k: [64][72]
#define HEADS_OFF 8704  // 64*136
#define HEAD_SZ 7424    // q 2560 + k 2560 + vt 2304
#define LDS_ELEMS 38400 // 76.8 KB -> 2 blocks/CU

__device__ __forceinline__ u16 f2bf(float f) {
    __hip_bfloat16 h = __float2bfloat16(f);
    return __builtin_bit_cast(u16, h);
}

// Pack weights into MFMA B-fragment order + build padded bias matrix.
// pkq: [(kt*24+ot)*64+lane]*8+r  = qkv_w[o][k], o=ot*16+(lane&15), k=kt*32+8*(lane>>4)+r
// pkp: same with 8 o-tiles       = proj_w[o][k]
// bM : [h][64][64] fp32, zero-padded past 49
__global__ void prep_kernel(const float* __restrict__ qkv_w,
                            const float* __restrict__ proj_w,
                            const float* __restrict__ rpb,
                            const int* __restrict__ rpi,
                            u16* __restrict__ pkq, u16* __restrict__ pkp,
                            float* __restrict__ bM) {
    int idx = blockIdx.x * blockDim.x + threadIdx.x;
    if (idx < 49152) {
        int r = idx & 7, lane = (idx >> 3) & 63, tile = idx >> 9;
        int ot = tile % 24, kt = tile / 24;
        int o = ot * 16 + (lane & 15);
        int k = kt * 32 + ((lane >> 4) << 3) + r;
        pkq[idx] = f2bf(qkv_w[o * CDIM + k]);
    } else if (idx < 65536) {
        int i2 = idx - 49152;
        int r = i2 & 7, lane = (i2 >> 3) & 63, tile = i2 >> 9;
        int ot = tile & 7, kt = tile >> 3;
        int o = ot * 16 + (lane & 15);
        int k = kt * 32 + ((lane >> 4) << 3) + r;
        pkp[i2] = f2bf(proj_w[o * CDIM + k]);
    } else if (idx < 81920) {
        int i3 = idx - 65536;
        int j = i3 & 63, i = (i3 >> 6) & 63, h = i3 >> 12;
        bM[i3] = (i < NTOK && j < NTOK) ? rpb[rpi[i * NTOK + j] * NH + h] : 0.0f;
    }
}

__global__ __launch_bounds__(256, 2) void winattn_kernel(
    const float* __restrict__ x, const float* __restrict__ qkv_b,
    const float* __restrict__ proj_b,
    const u16* __restrict__ pkq, const u16* __restrict__ pkp,
    const float* __restrict__ bM, float* __restrict__ out) {
    __shared__ __align__(16) u16 smem[LDS_ELEMS];
    const int b = blockIdx.x;
    const int tid = threadIdx.x;
    const int wave = tid >> 6, lane = tid & 63;
    const int g = lane >> 4, lr = lane & 15;

    u16* xt = smem; // [64][XT_STRIDE], later reused as attn-out (ao)

    // ---------- phase 1: x -> bf16 LDS (rows 49..63 zeroed) ----------
    const float* xp = x + (size_t)b * (NTOK * CDIM);
    for (int t = tid; t < (NTOK * CDIM) / 4; t += 256) {
        float4 v = reinterpret_cast<const float4*>(xp)[t];
        int lin = t * 4;
        int i = lin >> 7, c = lin & 127;
        uint2 pk;
        pk.x = (unsigned)f2bf(v.x) | ((unsigned)f2bf(v.y) << 16);
        pk.y = (unsigned)f2bf(v.z) | ((unsigned)f2bf(v.w) << 16);
        *reinterpret_cast<uint2*>(&xt[i * XT_STRIDE + c]) = pk;
    }
    for (int t = tid; t < 15 * XT_STRIDE; t += 256) xt[NTOK * XT_STRIDE + t] = 0;
    __syncthreads();

    // ---------- phase 2: QKV GEMM: [64x128] @ [128x384] ----------
    f32x4 acc[4][6] = {};
    const s16x8* pkqv = reinterpret_cast<const s16x8*>(pkq);
#pragma unroll
    for (int kt = 0; kt < 4; ++kt) {
        s16x8 af[4];
#pragma unroll
        for (int mt = 0; mt < 4; ++mt)
            af[mt] = *reinterpret_cast<const s16x8*>(&xt[(mt * 16 + lr) * XT_STRIDE + kt * 32 + g * 8]);
        s16x8 bfr[6];
#pragma unroll
        for (int t = 0; t < 6; ++t)
            bfr[t] = pkqv[(kt * 24 + wave * 6 + t) * 64 + lane];
#pragma unroll
        for (int mt = 0; mt < 4; ++mt)
#pragma unroll
            for (int t = 0; t < 6; ++t)
                acc[mt][t] = __builtin_amdgcn_mfma_f32_16x16x32_bf16(af[mt], bfr[t], acc[mt][t], 0, 0, 0);
    }

    // scatter Q(scaled)/K/V(transposed) to per-head LDS
    const float scale = 0.17677669529663687f; // 32^-0.5
#pragma unroll
    for (int t = 0; t < 6; ++t) {
        int o = (wave * 6 + t) * 16 + lr;
        float bias = qkv_b[o];
        int kind = o >> 7;        // 0=Q 1=K 2=V
        int oo = o & 127;
        int h = oo >> 5, d = oo & 31;
        u16* base = smem + HEADS_OFF + h * HEAD_SZ;
#pragma unroll
        for (int mt = 0; mt < 4; ++mt)
#pragma unroll
            for (int r = 0; r < 4; ++r) {
                int i = mt * 16 + g * 4 + r;
                float val = acc[mt][t][r] + bias;
                if (kind == 0)      base[i * QK_STRIDE + d] = f2bf(val * scale);
                else if (kind == 1) base[2560 + i * QK_STRIDE + d] = f2bf(val);
                else                base[5120 + d * VT_STRIDE + i] = f2bf(val);
            }
    }
    __syncthreads();

    // ---------- phase 3: attention, wave handles head = wave ----------
    u16* qb = smem + HEADS_OFF + wave * HEAD_SZ;
    u16* kb = qb + 2560;
    u16* vtb = qb + 5120;
    u16* pb = qb; // P aliases q+k (same wave only)

    f32x4 s[4][4] = {};
    {
        s16x8 aq[4], bk[4];
#pragma unroll
        for (int mt = 0; mt < 4; ++mt)
            aq[mt] = *reinterpret_cast<const s16x8*>(&qb[(mt * 16 + lr) * QK_STRIDE + g * 8]);
#pragma unroll
        for (int jt = 0; jt < 4; ++jt)
            bk[jt] = *reinterpret_cast<const s16x8*>(&kb[(jt * 16 + lr) * QK_STRIDE + g * 8]);
#pragma unroll
        for (int mt = 0; mt < 4; ++mt)
#pragma unroll
            for (int jt = 0; jt < 4; ++jt)
                s[mt][jt] = __builtin_amdgcn_mfma_f32_16x16x32_bf16(aq[mt], bk[jt], s[mt][jt], 0, 0, 0);
    }
    // bias + mask
    const float* bMh = bM + wave * 4096;
#pragma unroll
    for (int mt = 0; mt < 4; ++mt)
#pragma unroll
        for (int jt = 0; jt < 4; ++jt) {
            int jj = jt * 16 + lr;
            bool valid = jj < NTOK;
            int i0 = mt * 16 + g * 4;
#pragma unroll
            for (int r = 0; r < 4; ++r) {
                float bv = bMh[(i0 + r) * 64 + jj];
                s[mt][jt][r] = valid ? (s[mt][jt][r] + bv) : -1e30f;
            }
        }
    // wave-parallel row softmax (16-lane groups via shfl_xor)
#pragma unroll
    for (int mt = 0; mt < 4; ++mt)
#pragma unroll
        for (int r = 0; r < 4; ++r) {
            float m = fmaxf(fmaxf(s[mt][0][r], s[mt][1][r]), fmaxf(s[mt][2][r], s[mt][3][r]));
#pragma unroll
            for (int msk = 1; msk < 16; msk <<= 1) m = fmaxf(m, __shfl_xor(m, msk, 64));
            float sum = 0.f;
#pragma unroll
            for (int jt = 0; jt < 4; ++jt) {
                float e = __expf(s[mt][jt][r] - m);
                s[mt][jt][r] = e;
                sum += e;
            }
#pragma unroll
            for (int msk = 1; msk < 16; msk <<= 1) sum += __shfl_xor(sum, msk, 64);
            float inv = 1.0f / sum;
#pragma unroll
            for (int jt = 0; jt < 4; ++jt) s[mt][jt][r] *= inv;
        }
    __syncthreads(); // all QK^T LDS reads done before P overwrites q/k region
    // write P (bf16) row-major [64][72]
#pragma unroll
    for (int mt = 0; mt < 4; ++mt)
#pragma unroll
        for (int jt = 0; jt < 4; ++jt) {
            int jj = jt * 16 + lr;
#pragma unroll
            for (int r = 0; r < 4; ++r) {
                int i = mt * 16 + g * 4 + r;
                pb[i * VT_STRIDE + jj] = f2bf(s[mt][jt][r]);
            }
        }
    __syncthreads();

    // PV: [64x64] @ [64x32]
    f32x4 ov[4][2] = {};
#pragma unroll
    for (int kk = 0; kk < 2; ++kk) {
        s16x8 ap[4], bv[2];
#pragma unroll
        for (int mt = 0; mt < 4; ++mt)
            ap[mt] = *reinterpret_cast<const s16x8*>(&pb[(mt * 16 + lr) * VT_STRIDE + kk * 32 + g * 8]);
#pragma unroll
        for (int nt = 0; nt < 2; ++nt)
            bv[nt] = *reinterpret_cast<const s16x8*>(&vtb[(nt * 16 + lr) * VT_STRIDE + kk * 32 + g * 8]);
#pragma unroll
        for (int mt = 0; mt < 4; ++mt)
#pragma unroll
            for (int nt = 0; nt < 2; ++nt)
                ov[mt][nt] = __builtin_amdgcn_mfma_f32_16x16x32_bf16(ap[mt], bv[nt], ov[mt][nt], 0, 0, 0);
    }
    // write attn-out tile (aliases xt; xt reads finished at phase-2 barrier)
    u16* ao = smem;
#pragma unroll
    for (int mt = 0; mt < 4; ++mt)
#pragma unroll
        for (int nt = 0; nt < 2; ++nt)
#pragma unroll
            for (int r = 0; r < 4; ++r) {
                int i = mt * 16 + g * 4 + r;
                int d = nt * 16 + lr;
                ao[i * XT_STRIDE + wave * 32 + d] = f2bf(ov[mt][nt][r]);
            }
    __syncthreads();

    // ---------- phase 4: proj GEMM [64x128]@[128x128] + store ----------
    f32x4 pacc[4][2] = {};
    const s16x8* pkpv = reinterpret_cast<const s16x8*>(pkp);
#pragma unroll
    for (int kt = 0; kt < 4; ++kt) {
        s16x8 af[4], bfr[2];
#pragma unroll
        for (int mt = 0; mt < 4; ++mt)
            af[mt] = *reinterpret_cast<const s16x8*>(&ao[(mt * 16 + lr) * XT_STRIDE + kt * 32 + g * 8]);
#pragma unroll
        for (int t = 0; t < 2; ++t)
            bfr[t] = pkpv[(kt * 8 + wave * 2 + t) * 64 + lane];
#pragma unroll
        for (int mt = 0; mt < 4; ++mt)
#pragma unroll
            for (int t = 0; t < 2; ++t)
                pacc[mt][t] = __builtin_amdgcn_mfma_f32_16x16x32_bf16(af[mt], bfr[t], pacc[mt][t], 0, 0, 0);
    }
    float* outp = out + (size_t)b * (NTOK * CDIM);
#pragma unroll
    for (int t = 0; t < 2; ++t) {
        int oc = (wave * 2 + t) * 16 + lr;
        float pbv = proj_b[oc];
#pragma unroll
        for (int mt = 0; mt < 4; ++mt)
#pragma unroll
            for (int r = 0; r < 4; ++r) {
                int i = mt * 16 + g * 4 + r;
                if (i < NTOK) outp[(size_t)i * CDIM + oc] = pacc[mt][t][r] + pbv;
            }
    }
}

extern "C" void kernel_launch(void* const* d_in, const int* in_sizes, int n_in,
                              void* d_out, int out_size, void* d_ws, size_t ws_size,
                              hipStream_t stream) {
    const float* x      = (const float*)d_in[0];
    const float* qkv_w  = (const float*)d_in[1];
    const float* qkv_b  = (const float*)d_in[2];
    const float* proj_w = (const float*)d_in[3];
    const float* proj_b = (const float*)d_in[4];
    const float* rpb    = (const float*)d_in[5];
    const int*   rpi    = (const int*)d_in[6];
    float* out = (float*)d_out;

    u16*   pkq = (u16*)d_ws;                         // 49152 bf16 (98304 B)
    u16*   pkp = pkq + 49152;                        // 16384 bf16 (32768 B)
    float* bM  = (float*)((char*)d_ws + 131072);     // 4*64*64 fp32 (65536 B)

    prep_kernel<<<320, 256, 0, stream>>>(qkv_w, proj_w, rpb, rpi, pkq, pkp, bM);
    winattn_kernel<<<NWIN, 256, 0, stream>>>(x, qkv_b, proj_b, pkq, pkp, bM, out);
}

// Round 2
// 102.179 us; speedup vs baseline: 1.7187x; 1.7187x over previous
//
#include <hip/hip_runtime.h>
#include <hip/hip_bf16.h>

typedef __attribute__((ext_vector_type(8))) short s16x8;
typedef __attribute__((ext_vector_type(4))) float f32x4;
typedef unsigned short u16;

#define NTOK 49
#define CDIM 128
#define NH 4
#define NWIN 4096

// LDS plan (u16 units). Total 25600 u16 = 51200 B -> 3 blocks/CU.
//  phase 1-2: xt [64][136] at 0 (8704 u16)
//  per-head region (w*6400): q [64][40] at 0, k [64][40] at 2560
//    after S^T reads: P [64][64] XOR-swizzled at 0 (4096), vt [32][72] at 4096 (2304)
//  phase 4: ao [64][136] at 0
#define XT_STRIDE 136
#define QK_STRIDE 40
#define VT_STRIDE 72
#define HEAD_SZ 6400
#define K_OFF 2560
#define VT_OFF 4096
#define LDS_ELEMS 25600

__device__ __forceinline__ u16 f2bf(float f) {
    __hip_bfloat16 h = __float2bfloat16(f);
    return __builtin_bit_cast(u16, h);
}
__device__ __forceinline__ unsigned pk2(float a, float b) {
    return (unsigned)f2bf(a) | ((unsigned)f2bf(b) << 16);
}

// pkq: [(kt*24+ot)*64+lane]*8+r = qkv_w[o][k], o=ot*16+(lane&15), k=kt*32+8*(lane>>4)+r
// pkp: same with 8 o-tiles      = proj_w[o][k]
// bMv: [h][mt][nt][g][lr][r] fp32 = bias[q=16nt+lr][j=16mt+4g+r], zero-padded
__global__ void prep_kernel(const float* __restrict__ qkv_w,
                            const float* __restrict__ proj_w,
                            const float* __restrict__ rpb,
                            const int* __restrict__ rpi,
                            u16* __restrict__ pkq, u16* __restrict__ pkp,
                            float* __restrict__ bMv) {
    int idx = blockIdx.x * blockDim.x + threadIdx.x;
    if (idx < 49152) {
        int r = idx & 7, lane = (idx >> 3) & 63, tile = idx >> 9;
        int ot = tile % 24, kt = tile / 24;
        int o = ot * 16 + (lane & 15);
        int k = kt * 32 + ((lane >> 4) << 3) + r;
        pkq[idx] = f2bf(qkv_w[o * CDIM + k]);
    } else if (idx < 65536) {
        int i2 = idx - 49152;
        int r = i2 & 7, lane = (i2 >> 3) & 63, tile = i2 >> 9;
        int ot = tile & 7, kt = tile >> 3;
        int o = ot * 16 + (lane & 15);
        int k = kt * 32 + ((lane >> 4) << 3) + r;
        pkp[i2] = f2bf(proj_w[o * CDIM + k]);
    } else if (idx < 81920) {
        int i = idx - 65536;
        int r = i & 3, lr = (i >> 2) & 15, g = (i >> 6) & 3;
        int nt = (i >> 8) & 3, mt = (i >> 10) & 3, h = i >> 12;
        int q = nt * 16 + lr, j = mt * 16 + 4 * g + r;
        bMv[i] = (q < NTOK && j < NTOK) ? rpb[rpi[q * NTOK + j] * NH + h] : 0.0f;
    }
}

__global__ __launch_bounds__(256, 3) void winattn_kernel(
    const float* __restrict__ x, const float* __restrict__ qkv_b,
    const float* __restrict__ proj_b,
    const u16* __restrict__ pkq, const u16* __restrict__ pkp,
    const float* __restrict__ bMv, float* __restrict__ out) {
    __shared__ __align__(16) u16 smem[LDS_ELEMS];
    const int b = blockIdx.x;
    const int tid = threadIdx.x;
    const int wave = tid >> 6, lane = tid & 63;
    const int g = lane >> 4, lr = lane & 15;

    u16* xt = smem; // [64][136]; aliased by head regions after barrier 2

    // ---------- phase 1: x -> bf16 LDS (rows 49..63 zeroed) ----------
    const float* xp = x + (size_t)b * (NTOK * CDIM);
    for (int t = tid; t < (NTOK * CDIM) / 4; t += 256) {
        float4 v = reinterpret_cast<const float4*>(xp)[t];
        int lin = t * 4;
        int i = lin >> 7, c = lin & 127;
        uint2 pkv;
        pkv.x = pk2(v.x, v.y);
        pkv.y = pk2(v.z, v.w);
        *reinterpret_cast<uint2*>(&xt[i * XT_STRIDE + c]) = pkv;
    }
    for (int t = tid; t < 15 * XT_STRIDE; t += 256) xt[NTOK * XT_STRIDE + t] = 0;
    __syncthreads();

    // ---------- phase 2: QKV GEMM, wave w computes head w's q,k,v (6 col-tiles) ----------
    f32x4 acc[4][6] = {};
    const s16x8* pkqv = reinterpret_cast<const s16x8*>(pkq);
#pragma unroll
    for (int kt = 0; kt < 4; ++kt) {
        s16x8 af[4];
#pragma unroll
        for (int mt = 0; mt < 4; ++mt)
            af[mt] = *reinterpret_cast<const s16x8*>(&xt[(mt * 16 + lr) * XT_STRIDE + kt * 32 + g * 8]);
        s16x8 bfr[6];
#pragma unroll
        for (int t = 0; t < 6; ++t) {
            int ot = (t >> 1) * 8 + 2 * wave + (t & 1);
            bfr[t] = pkqv[(kt * 24 + ot) * 64 + lane];
        }
#pragma unroll
        for (int mt = 0; mt < 4; ++mt)
#pragma unroll
            for (int t = 0; t < 6; ++t)
                acc[mt][t] = __builtin_amdgcn_mfma_f32_16x16x32_bf16(af[mt], bfr[t], acc[mt][t], 0, 0, 0);
    }
    __syncthreads(); // all xt reads done; head regions may now overwrite xt

    // scatter q (scaled) / k to own head region; v packed into registers
    u16* hb = smem + wave * HEAD_SZ;
    u16* qb = hb;
    u16* kb = hb + K_OFF;
    const float scale = 0.17677669529663687f; // 32^-0.5
    unsigned vpk[4][2][2];
#pragma unroll
    for (int t = 0; t < 6; ++t) {
        int sel = t >> 1, t1 = t & 1;
        int o = (sel * 8 + 2 * wave + t1) * 16 + lr;
        float bias = qkv_b[o];
        int d = t1 * 16 + lr;
#pragma unroll
        for (int mt = 0; mt < 4; ++mt) {
            if (sel == 0) {
#pragma unroll
                for (int r = 0; r < 4; ++r)
                    qb[(mt * 16 + 4 * g + r) * QK_STRIDE + d] = f2bf((acc[mt][t][r] + bias) * scale);
            } else if (sel == 1) {
#pragma unroll
                for (int r = 0; r < 4; ++r)
                    kb[(mt * 16 + 4 * g + r) * QK_STRIDE + d] = f2bf(acc[mt][t][r] + bias);
            } else {
                vpk[mt][t1][0] = pk2(acc[mt][t][0] + bias, acc[mt][t][1] + bias);
                vpk[mt][t1][1] = pk2(acc[mt][t][2] + bias, acc[mt][t][3] + bias);
            }
        }
    }
    asm volatile("s_waitcnt lgkmcnt(0)" ::: "memory");

    // ---------- phase 3: S^T = K·Q^T (wave-local) ----------
    f32x4 st[4][4] = {};
    {
        s16x8 ak[4], bq[4];
#pragma unroll
        for (int mt = 0; mt < 4; ++mt)
            ak[mt] = *reinterpret_cast<const s16x8*>(&kb[(mt * 16 + lr) * QK_STRIDE + g * 8]);
#pragma unroll
        for (int nt = 0; nt < 4; ++nt)
            bq[nt] = *reinterpret_cast<const s16x8*>(&qb[(nt * 16 + lr) * QK_STRIDE + g * 8]);
#pragma unroll
        for (int mt = 0; mt < 4; ++mt)
#pragma unroll
            for (int nt = 0; nt < 4; ++nt)
                st[mt][nt] = __builtin_amdgcn_mfma_f32_16x16x32_bf16(ak[mt], bq[nt], st[mt][nt], 0, 0, 0);
    }
    // bias (vectorized) + mask j>=49; st[mt][nt][r] = S[q=16nt+lr][j=16mt+4g+r]
    const f32x4* bv4 = reinterpret_cast<const f32x4*>(bMv);
#pragma unroll
    for (int mt = 0; mt < 4; ++mt)
#pragma unroll
        for (int nt = 0; nt < 4; ++nt) {
            f32x4 bb = bv4[(((wave * 4 + mt) * 4 + nt) * 4 + g) * 16 + lr];
#pragma unroll
            for (int r = 0; r < 4; ++r) {
                float v = st[mt][nt][r] + bb[r];
                if (mt == 3) v = (g == 0 && r == 0) ? v : -1e30f;
                st[mt][nt][r] = v;
            }
        }
    // softmax over j: per-lane 16 values, then 2-shuffle cross-g reduce
#pragma unroll
    for (int nt = 0; nt < 4; ++nt) {
        float m = st[0][nt][0];
#pragma unroll
        for (int mt = 0; mt < 4; ++mt)
#pragma unroll
            for (int r = 0; r < 4; ++r) m = fmaxf(m, st[mt][nt][r]);
        m = fmaxf(m, __shfl_xor(m, 16, 64));
        m = fmaxf(m, __shfl_xor(m, 32, 64));
        float s = 0.f;
#pragma unroll
        for (int mt = 0; mt < 4; ++mt)
#pragma unroll
            for (int r = 0; r < 4; ++r) {
                float e = __expf(st[mt][nt][r] - m);
                st[mt][nt][r] = e;
                s += e;
            }
        s += __shfl_xor(s, 16, 64);
        s += __shfl_xor(s, 32, 64);
        float inv = 1.0f / s;
#pragma unroll
        for (int mt = 0; mt < 4; ++mt)
#pragma unroll
            for (int r = 0; r < 4; ++r) st[mt][nt][r] *= inv;
    }
    // write P [64][64] XOR-swizzled (packed b64) over q/k region; vt from regs over k tail
    char* pB = reinterpret_cast<char*>(hb);
    u16* vtb = hb + VT_OFF;
#pragma unroll
    for (int mt = 0; mt < 4; ++mt)
#pragma unroll
        for (int nt = 0; nt < 4; ++nt) {
            uint2 w2;
            w2.x = pk2(st[mt][nt][0], st[mt][nt][1]);
            w2.y = pk2(st[mt][nt][2], st[mt][nt][3]);
            int q = nt * 16 + lr;
            int off = (q * 128 + mt * 32 + g * 8) ^ ((q & 7) << 4);
            *reinterpret_cast<uint2*>(pB + off) = w2;
        }
#pragma unroll
    for (int mt = 0; mt < 4; ++mt)
#pragma unroll
        for (int tv = 0; tv < 2; ++tv) {
            uint2 w2;
            w2.x = vpk[mt][tv][0];
            w2.y = vpk[mt][tv][1];
            *reinterpret_cast<uint2*>(&vtb[(tv * 16 + lr) * VT_STRIDE + mt * 16 + 4 * g]) = w2;
        }
    asm volatile("s_waitcnt lgkmcnt(0)" ::: "memory");

    // PV: [64q x 64tok] @ [64tok x 32d]
    f32x4 ov[4][2] = {};
    {
        s16x8 pa[4][2], bv[2][2];
#pragma unroll
        for (int qmt = 0; qmt < 4; ++qmt)
#pragma unroll
            for (int kk = 0; kk < 2; ++kk) {
                int off = (((qmt * 16 + lr) * 128) + kk * 64 + g * 16) ^ ((lr & 7) << 4);
                pa[qmt][kk] = *reinterpret_cast<const s16x8*>(pB + off);
            }
#pragma unroll
        for (int nt = 0; nt < 2; ++nt)
#pragma unroll
            for (int kk = 0; kk < 2; ++kk)
                bv[nt][kk] = *reinterpret_cast<const s16x8*>(&vtb[(nt * 16 + lr) * VT_STRIDE + kk * 32 + g * 8]);
#pragma unroll
        for (int qmt = 0; qmt < 4; ++qmt)
#pragma unroll
            for (int nt = 0; nt < 2; ++nt)
#pragma unroll
                for (int kk = 0; kk < 2; ++kk)
                    ov[qmt][nt] = __builtin_amdgcn_mfma_f32_16x16x32_bf16(pa[qmt][kk], bv[nt][kk], ov[qmt][nt], 0, 0, 0);
    }
    __syncthreads(); // all waves done with their head regions; ao may alias

    // ---------- write attn-out tile [64][136] ----------
    u16* ao = smem;
#pragma unroll
    for (int qmt = 0; qmt < 4; ++qmt)
#pragma unroll
        for (int nt = 0; nt < 2; ++nt)
#pragma unroll
            for (int r = 0; r < 4; ++r)
                ao[(qmt * 16 + 4 * g + r) * XT_STRIDE + wave * 32 + nt * 16 + lr] = f2bf(ov[qmt][nt][r]);
    __syncthreads();

    // ---------- phase 4: proj GEMM [64x128]@[128x128] + store ----------
    f32x4 pacc[4][2] = {};
    const s16x8* pkpv = reinterpret_cast<const s16x8*>(pkp);
#pragma unroll
    for (int kt = 0; kt < 4; ++kt) {
        s16x8 af[4], bfr[2];
#pragma unroll
        for (int mt = 0; mt < 4; ++mt)
            af[mt] = *reinterpret_cast<const s16x8*>(&ao[(mt * 16 + lr) * XT_STRIDE + kt * 32 + g * 8]);
#pragma unroll
        for (int t = 0; t < 2; ++t)
            bfr[t] = pkpv[(kt * 8 + wave * 2 + t) * 64 + lane];
#pragma unroll
        for (int mt = 0; mt < 4; ++mt)
#pragma unroll
            for (int t = 0; t < 2; ++t)
                pacc[mt][t] = __builtin_amdgcn_mfma_f32_16x16x32_bf16(af[mt], bfr[t], pacc[mt][t], 0, 0, 0);
    }
    float* outp = out + (size_t)b * (NTOK * CDIM);
#pragma unroll
    for (int t = 0; t < 2; ++t) {
        int oc = (wave * 2 + t) * 16 + lr;
        float pbv = proj_b[oc];
#pragma unroll
        for (int mt = 0; mt < 4; ++mt)
#pragma unroll
            for (int r = 0; r < 4; ++r) {
                int i = mt * 16 + 4 * g + r;
                if (i < NTOK) outp[(size_t)i * CDIM + oc] = pacc[mt][t][r] + pbv;
            }
    }
}

extern "C" void kernel_launch(void* const* d_in, const int* in_sizes, int n_in,
                              void* d_out, int out_size, void* d_ws, size_t ws_size,
                              hipStream_t stream) {
    const float* x      = (const float*)d_in[0];
    const float* qkv_w  = (const float*)d_in[1];
    const float* qkv_b  = (const float*)d_in[2];
    const float* proj_w = (const float*)d_in[3];
    const float* proj_b = (const float*)d_in[4];
    const float* rpb    = (const float*)d_in[5];
    const int*   rpi    = (const int*)d_in[6];
    float* out = (float*)d_out;

    u16*   pkq = (u16*)d_ws;                         // 49152 bf16 (98304 B)
    u16*   pkp = pkq + 49152;                        // 16384 bf16 (32768 B)
    float* bMv = (float*)((char*)d_ws + 131072);     // 16384 fp32 (65536 B)

    prep_kernel<<<320, 256, 0, stream>>>(qkv_w, proj_w, rpb, rpi, pkq, pkp, bMv);
    winattn_kernel<<<NWIN, 256, 0, stream>>>(x, qkv_b, proj_b, pkq, pkp, bMv, out);
}